// Round 5
// baseline (476.155 us; speedup 1.0000x reference)
//
#include <hip/hip_runtime.h>

// ---------------- problem constants ----------------
#define CM_    76
#define CMP_   80

typedef __attribute__((ext_vector_type(4))) float f32x4;
typedef __attribute__((ext_vector_type(8))) short bf16x8;

__device__ __forceinline__ unsigned short f2bf(float f) {
  union { float f; unsigned u; } v; v.f = f;
  unsigned r = v.u + 0x7FFFu + ((v.u >> 16) & 1u);
  return (unsigned short)(r >> 16);
}
__device__ __forceinline__ unsigned pack2(float a, float b) {
  return (unsigned)f2bf(a) | ((unsigned)f2bf(b) << 16);
}

// ---------------- workspace layout (float offsets; all 16B-aligned) ----------------
#define OFF_BK2     0            // [64][80] f32 (init cbb / -1e30 pads, k2 atomics add)
#define OFF_INV     5120         // [512] f32
#define OFF_ADD     5632         // [512] f32
#define OFF_WKBQ    6144         // [512] f32  (Wk@bq)
#define OFF_BQKADD  6656         // [512] f32  (Wq@bk)
#define OFF_CBB     7168         // [1] f32 (pad to 7172)
#define OFF_EXPSIM  7172         // bf16 [64][80][1024]
#define OFF_LOCALBF 2628612      // bf16 [64][80][512]
#define OFF_WQKT    3939332      // bf16 [64][80][512]
#define OFF_VWT     5250052     // bf16 [512][96]
#define OFF_WQWKT   5274628      // bf16 [512][512] (Wq@Wk^T)
#define OFF_WVWCT   5405700      // bf16 [512][512] (Wc^T@Wv^T)

// ---------------- kW (one-off): WqWkT / WvWcT + (blk.x==64) scalar pre ----------------
// grid (65, 2)
__global__ __launch_bounds__(256) void kW_pre(
    const float* __restrict__ Wq, const float* __restrict__ Wk,
    const float* __restrict__ Wv, const float* __restrict__ Wc,
    const float* __restrict__ bq, const float* __restrict__ bk,
    const float* __restrict__ gamma, const float* __restrict__ beta,
    const float* __restrict__ mean, const float* __restrict__ var,
    unsigned short* __restrict__ WqWkT, unsigned short* __restrict__ WvWcT,
    float* __restrict__ wkbq, float* __restrict__ bqkadd,
    float* __restrict__ invp, float* __restrict__ addp, float* __restrict__ cbbp) {
  const int sel = blockIdx.y;
  if (blockIdx.x == 64) {
    const int c = sel * 256 + threadIdx.x;
    const float* wkr = Wk + (size_t)c * 256;
    const float* wqr = Wq + (size_t)c * 256;
    float s1 = 0.f, s2 = 0.f;
    for (int m = 0; m < 256; ++m) { s1 += wkr[m] * bq[m]; s2 += wqr[m] * bk[m]; }
    wkbq[c] = s1; bqkadd[c] = s2;
    float iv = gamma[c] * rsqrtf(var[c] + 1e-5f);
    invp[c] = iv; addp[c] = beta[c] - mean[c] * iv;
    if (c == 0) {
      float s = 0.f;
      for (int m = 0; m < 256; ++m) s += bq[m] * bk[m];
      cbbp[0] = s;
    }
    return;
  }
  const int r0 = (blockIdx.x >> 3) * 64, c0 = (blockIdx.x & 7) * 64;
  __shared__ __align__(16) unsigned short Asm[64 * 40];
  __shared__ __align__(16) unsigned short Bsm[64 * 40];
  const int t = threadIdx.x, lane = t & 63, w = t >> 6;
  const int lo = lane & 15, hi = lane >> 4;
  f32x4 acc[4];
#pragma unroll
  for (int cT = 0; cT < 4; ++cT) acc[cT] = (f32x4){0.f, 0.f, 0.f, 0.f};
  const float* Bsrc = sel ? Wv : Wk;
  for (int kc = 0; kc < 8; ++kc) {
    const int k0 = kc * 32;
    __syncthreads();
    {
      int nn = t >> 2, mq = (t & 3) * 8;
      const float* src = Bsrc + (size_t)(c0 + nn) * 256 + k0 + mq;
      float4 v0 = *(const float4*)src, v1 = *(const float4*)(src + 4);
      unsigned* d = (unsigned*)&Bsm[nn * 40 + mq];
      d[0] = pack2(v0.x, v0.y); d[1] = pack2(v0.z, v0.w);
      d[2] = pack2(v1.x, v1.y); d[3] = pack2(v1.z, v1.w);
    }
    if (sel == 0) {
      int r = t >> 2, mq = (t & 3) * 8;
      const float* src = Wq + (size_t)(r0 + r) * 256 + k0 + mq;
      float4 v0 = *(const float4*)src, v1 = *(const float4*)(src + 4);
      unsigned* d = (unsigned*)&Asm[r * 40 + mq];
      d[0] = pack2(v0.x, v0.y); d[1] = pack2(v0.z, v0.w);
      d[2] = pack2(v1.x, v1.y); d[3] = pack2(v1.z, v1.w);
    } else {
      int m = t >> 3, c2q = (t & 7) * 8;
      const float* src = Wc + (size_t)(k0 + m) * 512 + r0 + c2q;
      float4 v0 = *(const float4*)src, v1 = *(const float4*)(src + 4);
      Asm[(c2q + 0) * 40 + m] = f2bf(v0.x); Asm[(c2q + 1) * 40 + m] = f2bf(v0.y);
      Asm[(c2q + 2) * 40 + m] = f2bf(v0.z); Asm[(c2q + 3) * 40 + m] = f2bf(v0.w);
      Asm[(c2q + 4) * 40 + m] = f2bf(v1.x); Asm[(c2q + 5) * 40 + m] = f2bf(v1.y);
      Asm[(c2q + 6) * 40 + m] = f2bf(v1.z); Asm[(c2q + 7) * 40 + m] = f2bf(v1.w);
    }
    __syncthreads();
    bf16x8 afr = *(bf16x8*)(&Asm[(w * 16 + lo) * 40 + hi * 8]);
#pragma unroll
    for (int cT = 0; cT < 4; ++cT) {
      bf16x8 bfr = *(bf16x8*)(&Bsm[(cT * 16 + lo) * 40 + hi * 8]);
      acc[cT] = __builtin_amdgcn_mfma_f32_16x16x32_bf16(afr, bfr, acc[cT], 0, 0, 0);
    }
  }
  unsigned short* dst = sel ? WvWcT : WqWkT;
#pragma unroll
  for (int cT = 0; cT < 4; ++cT)
#pragma unroll
    for (int rr = 0; rr < 4; ++rr)
      dst[(size_t)(r0 + w * 16 + hi * 4 + rr) * 512 + c0 + cT * 16 + lo] = f2bf(acc[cT][rr]);
}

// ---------------- K1: stats + materialize expsim bf16 (scaled), init bk2 ----------------
// grid (80, 64)
__global__ __launch_bounds__(256) void k1_stats(
    const float* __restrict__ sim, float* __restrict__ pcs,
    const float* __restrict__ cbbp,
    unsigned short* __restrict__ expsim, float* __restrict__ bk2) {
  const int cm = blockIdx.x, inst = blockIdx.y;
  const int t = threadIdx.x;
  unsigned short* erow = expsim + (size_t)inst * 81920 + (size_t)cm * 1024;
  if (cm >= CM_) {
    ((unsigned long long*)erow)[t] = 0ull;
    if (t == 0) bk2[inst * CMP_ + cm] = -1e30f;
    return;
  }
  const int b = inst >> 4, n = inst & 15, bh = n >> 2, bw = n & 3;
  const float* base = sim + ((size_t)(b * CM_ + cm) << 14);
  const int p0 = t * 4;
  const int pix0 = ((bh * 32 + (p0 >> 5)) << 7) + bw * 32 + (p0 & 31);
  float4 vv = *(const float4*)(base + pix0);
  float lsum = vv.x + vv.y + vv.z + vv.w;
  float lmax = fmaxf(fmaxf(vv.x, vv.y), fmaxf(vv.z, vv.w));
#pragma unroll
  for (int off = 32; off; off >>= 1) {
    lsum += __shfl_down(lsum, off);
    lmax = fmaxf(lmax, __shfl_down(lmax, off));
  }
  __shared__ float ssum[4], smax[4], bc[2];
  const int wid = t >> 6;
  if ((t & 63) == 0) { ssum[wid] = lsum; smax[wid] = lmax; }
  __syncthreads();
  if (t == 0) {
    bc[0] = ssum[0] + ssum[1] + ssum[2] + ssum[3];
    bc[1] = fmaxf(fmaxf(smax[0], smax[1]), fmaxf(smax[2], smax[3]));
  }
  __syncthreads();
  const float M = bc[1];
  float e0 = __expf(vv.x - M), e1 = __expf(vv.y - M);
  float e2 = __expf(vv.z - M), e3 = __expf(vv.w - M);
  float le = (e0 + e1) + (e2 + e3);
#pragma unroll
  for (int off = 32; off; off >>= 1) le += __shfl_down(le, off);
  if ((t & 63) == 0) ssum[wid] = le;
  __syncthreads();
  if (t == 0) {
    float E = ssum[0] + ssum[1] + ssum[2] + ssum[3];
    float conf = bc[0] * (1.f / 1024.f);
    pcs[((b * CM_ + cm) << 4) + n] = conf;
    bk2[inst * CMP_ + cm] = cbbp[0];
    bc[0] = conf / E;
  }
  __syncthreads();
  const float sc = bc[0];
  unsigned l32 = pack2(sc * e0, sc * e1);
  unsigned h32 = pack2(sc * e2, sc * e3);
  *(unsigned long long*)(&erow[p0]) = (unsigned long long)l32 | ((unsigned long long)h32 << 32);
}

// ---------------- K2 (MFMA): local bf16 = expsim @ x^T ; bk2 += local.wkbq ----------------
// grid (32, 64): ccc = 16-ch tile, inst. 4 waves k-split over pixel quarters; LDS reduce.
__global__ __launch_bounds__(256) void k2_local(
    const float* __restrict__ x, const unsigned short* __restrict__ expsim,
    const float* __restrict__ wkbq,
    unsigned short* __restrict__ local_bf, float* __restrict__ bk2) {
  const int ccc = blockIdx.x, inst = blockIdx.y;
  const int b = inst >> 4, n = inst & 15, bh = n >> 2, bw = n & 3;
  const int t = threadIdx.x, lane = t & 63, w = t >> 6;
  const int lo = lane & 15, hi = lane >> 4;
  const int ch0 = ccc * 16;
  __shared__ float Red[4 * 80 * 17];   // 21.8 KB
  const unsigned short* Abase = expsim + (size_t)inst * 81920;
  const float* xch = x + (((size_t)(b * 512 + ch0 + lo)) << 14) + bw * 32 + hi * 8;
  const int rowb = bh * 32 + w * 8;
  f32x4 acc[5];
#pragma unroll
  for (int T = 0; T < 5; ++T) acc[T] = (f32x4){0.f, 0.f, 0.f, 0.f};
#pragma unroll
  for (int ks = 0; ks < 8; ++ks) {
    const int k = w * 256 + ks * 32 + hi * 8;
    const float* xr = xch + ((size_t)(rowb + ks) << 7);
    float4 v0 = *(const float4*)(xr);
    float4 v1 = *(const float4*)(xr + 4);
    bf16x8 bfr;
    ((unsigned*)&bfr)[0] = pack2(v0.x, v0.y);
    ((unsigned*)&bfr)[1] = pack2(v0.z, v0.w);
    ((unsigned*)&bfr)[2] = pack2(v1.x, v1.y);
    ((unsigned*)&bfr)[3] = pack2(v1.z, v1.w);
#pragma unroll
    for (int T = 0; T < 5; ++T) {
      bf16x8 afr = *(const bf16x8*)(Abase + (size_t)(T * 16 + lo) * 1024 + k);
      acc[T] = __builtin_amdgcn_mfma_f32_16x16x32_bf16(afr, bfr, acc[T], 0, 0, 0);
    }
  }
  // D: col(lo)=ch, row=cm -> stash partials
#pragma unroll
  for (int T = 0; T < 5; ++T)
#pragma unroll
    for (int r = 0; r < 4; ++r)
      Red[w * 1360 + (T * 16 + hi * 4 + r) * 17 + lo] = acc[T][r];
  __syncthreads();
  // epilogue: 1280 outputs over 256 threads
  const int ch = t & 15, cmg = t >> 4;
  const float wk = wkbq[ch0 + ch];
#pragma unroll
  for (int j = 0; j < 5; ++j) {
    int cm = cmg + 16 * j;
    float av = Red[cm * 17 + ch] + Red[1360 + cm * 17 + ch] +
               Red[2720 + cm * 17 + ch] + Red[4080 + cm * 17 + ch];
    local_bf[((size_t)inst * CMP_ + cm) * 512 + ch0 + ch] = f2bf(av);
    float p = av * wk;
    p += __shfl_xor(p, 1); p += __shfl_xor(p, 2);
    p += __shfl_xor(p, 4); p += __shfl_xor(p, 8);
    if (ch == 0 && cm < CM_) atomicAdd(&bk2[inst * CMP_ + cm], p);
  }
}

// ---------------- k3n (MFMA): Wqkt[inst][cm][c] = local@WqWkT^T + bqkadd ----------------
// grid (8, 64): 64-c tile per block, 16-c per wave. No LDS.
__global__ __launch_bounds__(256) void k3n_wqkt(
    const unsigned short* __restrict__ local_bf, const unsigned short* __restrict__ WqWkT,
    const float* __restrict__ bqkadd, unsigned short* __restrict__ Wqkt) {
  const int blkc = blockIdx.x, inst = blockIdx.y;
  const int t = threadIdx.x, lane = t & 63, w = t >> 6;
  const int lo = lane & 15, hi = lane >> 4;
  const int cbase = blkc * 64 + w * 16;
  f32x4 acc[5];
  {
    float bv_ = bqkadd[cbase + lo];
#pragma unroll
    for (int T = 0; T < 5; ++T) acc[T] = (f32x4){bv_, bv_, bv_, bv_};
  }
  const unsigned short* Abase = local_bf + (size_t)inst * 40960;
#pragma unroll 4
  for (int ks = 0; ks < 16; ++ks) {
    const int k = ks * 32 + hi * 8;
    bf16x8 bfr = *(const bf16x8*)(WqWkT + (size_t)(cbase + lo) * 512 + k);
#pragma unroll
    for (int T = 0; T < 5; ++T) {
      bf16x8 af = *(const bf16x8*)(Abase + (size_t)(T * 16 + lo) * 512 + k);
      acc[T] = __builtin_amdgcn_mfma_f32_16x16x32_bf16(af, bfr, acc[T], 0, 0, 0);
    }
  }
#pragma unroll
  for (int T = 0; T < 5; ++T)
#pragma unroll
    for (int r = 0; r < 4; ++r) {
      int cm = T * 16 + hi * 4 + r;
      Wqkt[(size_t)inst * 40960 + (size_t)cm * 512 + cbase + lo] = f2bf(acc[T][r]);
    }
}

// ---------------- kV (MFMA): vWt[c2][cm] = WvWcT@g^T + bvWc ----------------
// grid (8, 2)
__global__ __launch_bounds__(256) void kV_vwt(
    const unsigned short* __restrict__ WvWcT, const float* __restrict__ g,
    const float* __restrict__ bv, const float* __restrict__ Wc,
    unsigned short* __restrict__ vWt) {
  const int blk = blockIdx.x, half = blockIdx.y;
  const int t = threadIdx.x, lane = t & 63, w = t >> 6;
  const int lo = lane & 15, hi = lane >> 4;
  __shared__ float bvp[4][64];
  __shared__ float bvs[64];
  {
    int c2l = t & 63, part = t >> 6;
    float s = 0.f;
    for (int m = part * 64; m < part * 64 + 64; ++m)
      s += bv[m] * Wc[(size_t)m * 512 + blk * 64 + c2l];
    bvp[part][c2l] = s;
  }
  __syncthreads();
  if (t < 64) bvs[t] = bvp[0][t] + bvp[1][t] + bvp[2][t] + bvp[3][t];
  __syncthreads();
  const int r2 = blk * 64 + w * 16;
  f32x4 acc[3];
#pragma unroll
  for (int j = 0; j < 3; ++j) acc[j] = (f32x4){0.f, 0.f, 0.f, 0.f};
#pragma unroll 4
  for (int ks = 0; ks < 16; ++ks) {
    const int k = ks * 32 + hi * 8;
    bf16x8 afr = *(const bf16x8*)(WvWcT + (size_t)(r2 + lo) * 512 + k);
#pragma unroll
    for (int j = 0; j < 3; ++j) {
      int cm = (half * 3 + j) * 16 + lo;
      cm = cm > 75 ? 75 : cm;
      const float* gr = g + (size_t)cm * 512 + k;
      float4 v0 = *(const float4*)gr, v1 = *(const float4*)(gr + 4);
      bf16x8 bfr;
      ((unsigned*)&bfr)[0] = pack2(v0.x, v0.y);
      ((unsigned*)&bfr)[1] = pack2(v0.z, v0.w);
      ((unsigned*)&bfr)[2] = pack2(v1.x, v1.y);
      ((unsigned*)&bfr)[3] = pack2(v1.z, v1.w);
      acc[j] = __builtin_amdgcn_mfma_f32_16x16x32_bf16(afr, bfr, acc[j], 0, 0, 0);
    }
  }
#pragma unroll
  for (int j = 0; j < 3; ++j)
#pragma unroll
    for (int rr = 0; rr < 4; ++rr) {
      int c2g = blk * 64 + w * 16 + hi * 4 + rr;
      vWt[(size_t)c2g * 96 + (half * 3 + j) * 16 + lo] =
          f2bf(acc[j][rr] + bvs[w * 16 + hi * 4 + rr]);
    }
}

// ---------------- K4 (MFMA): logits -> softmax -> y, 2-row blocks + 2-way k-split ----------------
// grid (16, 64): pt2 = img-row pair. waves: r = w&1 (row), h = w>>1 (k-half).
__global__ __launch_bounds__(256) void k4_attn(
    const float* __restrict__ x, const unsigned short* __restrict__ Wqkt,
    const float* __restrict__ bk2, const unsigned short* __restrict__ vWt,
    const float* __restrict__ inv_arr, const float* __restrict__ add_arr,
    float* __restrict__ y) {
  const int pt2 = blockIdx.x, inst = blockIdx.y;
  const int b = inst >> 4, n = inst & 15, bh = n >> 2, bw = n & 3;
  __shared__ __align__(16) char Ubuf[20736];       // union: Xs[4][32*72] (18.4KB) | Red[2][32][81] f32 (20.7KB)
  __shared__ unsigned short Att[2][32 * 96];       // 12.3 KB
  unsigned short* Xs = (unsigned short*)Ubuf;
  float* Red = (float*)Ubuf;
  const int t = threadIdx.x, lane = t & 63, w = t >> 6;
  const int lo = lane & 15, hi = lane >> 4;
  const int pq = lane & 7, chp0 = lane >> 3;
  const int r = w & 1, h = w >> 1;

  const int imgrow = bh * 32 + pt2 * 2 + r;
  const size_t pixbase = (size_t)imgrow * 128 + bw * 32;
  const size_t xrowbase = (((size_t)b * 512) << 14) + pixbase;
  const unsigned short* Wi = Wqkt + (size_t)inst * 40960;

  // ---- Phase 1: half the channels per wave ----
  f32x4 acc[2][5];
  if (h == 0) {
#pragma unroll
    for (int T = 0; T < 5; ++T) {
      f32x4 bv;
#pragma unroll
      for (int r4 = 0; r4 < 4; ++r4) bv[r4] = bk2[inst * CMP_ + T * 16 + hi * 4 + r4];
      acc[0][T] = bv; acc[1][T] = bv;
    }
  } else {
#pragma unroll
    for (int T = 0; T < 5; ++T) {
      acc[0][T] = (f32x4){0.f, 0.f, 0.f, 0.f};
      acc[1][T] = (f32x4){0.f, 0.f, 0.f, 0.f};
    }
  }
#pragma unroll
  for (int kci = 0; kci < 4; ++kci) {
    const int kc = h * 4 + kci;
#pragma unroll
    for (int i = 0; i < 4; ++i) {
      int chp = chp0 + i * 8;
      int ch = kc * 64 + chp * 2;
      const float* xa = x + xrowbase + ((size_t)ch << 14) + pq * 4;
      float4 va = *(const float4*)(xa);
      float4 vb = *(const float4*)(xa + 16384);
      unsigned short* dst = &Xs[w * 2304 + (pq * 4) * 72 + chp * 2];
      *(unsigned*)(dst + 0 * 72) = pack2(va.x, vb.x);
      *(unsigned*)(dst + 1 * 72) = pack2(va.y, vb.y);
      *(unsigned*)(dst + 2 * 72) = pack2(va.z, vb.z);
      *(unsigned*)(dst + 3 * 72) = pack2(va.w, vb.w);
    }
#pragma unroll
    for (int ks = 0; ks < 2; ++ks) {
      int kb = kc * 64 + ks * 32 + hi * 8;
      bf16x8 b0 = *(bf16x8*)(&Xs[w * 2304 + lo * 72 + ks * 32 + hi * 8]);
      bf16x8 b1 = *(bf16x8*)(&Xs[w * 2304 + (16 + lo) * 72 + ks * 32 + hi * 8]);
#pragma unroll
      for (int T = 0; T < 5; ++T) {
        bf16x8 afr = *(const bf16x8*)(Wi + (size_t)(T * 16 + lo) * 512 + kb);
        acc[0][T] = __builtin_amdgcn_mfma_f32_16x16x32_bf16(afr, b0, acc[0][T], 0, 0, 0);
        acc[1][T] = __builtin_amdgcn_mfma_f32_16x16x32_bf16(afr, b1, acc[1][T], 0, 0, 0);
      }
    }
  }
  __syncthreads();      // all phase-1 Xs reads done; Ubuf becomes Red
  if (h == 1) {
#pragma unroll
    for (int p = 0; p < 2; ++p)
#pragma unroll
      for (int T = 0; T < 5; ++T)
#pragma unroll
        for (int r4 = 0; r4 < 4; ++r4)
          Red[r * 2592 + (p * 16 + lo) * 81 + T * 16 + hi * 4 + r4] = acc[p][T][r4];
  }
  __syncthreads();
  // ---- Phase 2: h==0 waves merge + softmax, write Att[row] ----
  if (h == 0) {
#pragma unroll
    for (int p = 0; p < 2; ++p) {
#pragma unroll
      for (int T = 0; T < 5; ++T)
#pragma unroll
        for (int r4 = 0; r4 < 4; ++r4)
          acc[p][T][r4] += Red[r * 2592 + (p * 16 + lo) * 81 + T * 16 + hi * 4 + r4];
      float m = -1e30f;
#pragma unroll
      for (int T = 0; T < 5; ++T)
#pragma unroll
        for (int r4 = 0; r4 < 4; ++r4) m = fmaxf(m, acc[p][T][r4]);
      m = fmaxf(m, __shfl_xor(m, 16));
      m = fmaxf(m, __shfl_xor(m, 32));
      float e[5][4];
      float s = 0.f;
#pragma unroll
      for (int T = 0; T < 5; ++T)
#pragma unroll
        for (int r4 = 0; r4 < 4; ++r4) {
          float ev = __expf(acc[p][T][r4] - m); e[T][r4] = ev; s += ev;
        }
      s += __shfl_xor(s, 16);
      s += __shfl_xor(s, 32);
      float rinv = 1.f / s;
      int px = p * 16 + lo;
#pragma unroll
      for (int T = 0; T < 5; ++T) {
        unsigned l32 = pack2(e[T][0] * rinv, e[T][1] * rinv);
        unsigned h32 = pack2(e[T][2] * rinv, e[T][3] * rinv);
        *(unsigned long long*)(&Att[r][px * 96 + T * 16 + hi * 4]) =
            (unsigned long long)l32 | ((unsigned long long)h32 << 32);
      }
      *(unsigned long long*)(&Att[r][px * 96 + 80 + hi * 4]) = 0ull;
    }
  }
  __syncthreads();

  // ---- Phase 3: wave w -> row (w&1), channel group (w>>1) ----
  const int rr = w & 1, cgrp = w >> 1;
  const size_t pixb3 = (size_t)(bh * 32 + pt2 * 2 + rr) * 128 + bw * 32;
  bf16x8 bfr3[2][3];
#pragma unroll
  for (int p = 0; p < 2; ++p)
#pragma unroll
    for (int ks = 0; ks < 3; ++ks)
      bfr3[p][ks] = *(bf16x8*)(&Att[rr][(p * 16 + lo) * 96 + ks * 32 + hi * 8]);

  for (int cT = cgrp * 16; cT < cgrp * 16 + 16; ++cT) {
    f32x4 a0 = (f32x4){0.f, 0.f, 0.f, 0.f}, a1 = a0;
    const unsigned short* vr = vWt + (size_t)(cT * 16 + lo) * 96;
#pragma unroll
    for (int ks = 0; ks < 3; ++ks) {
      bf16x8 afr = *(const bf16x8*)(vr + ks * 32 + hi * 8);
      a0 = __builtin_amdgcn_mfma_f32_16x16x32_bf16(afr, bfr3[0][ks], a0, 0, 0, 0);
      a1 = __builtin_amdgcn_mfma_f32_16x16x32_bf16(afr, bfr3[1][ks], a1, 0, 0, 0);
    }
    f32x4 inv4 = *(const f32x4*)(inv_arr + cT * 16 + hi * 4);
    f32x4 add4 = *(const f32x4*)(add_arr + cT * 16 + hi * 4);
#pragma unroll
    for (int r4 = 0; r4 < 4; ++r4) {
      int ch = cT * 16 + hi * 4 + r4;
      float v0 = fmaxf(a0[r4] * inv4[r4] + add4[r4], 0.f);
      float v1 = fmaxf(a1[r4] * inv4[r4] + add4[r4], 0.f);
      size_t yb = (((size_t)(b * 512 + ch)) << 14) + pixb3;
      y[yb + lo] = v0;
      y[yb + 16 + lo] = v1;
    }
  }
}

// ---------------- host launch ----------------
extern "C" void kernel_launch(void* const* d_in, const int* in_sizes, int n_in,
                              void* d_out, int out_size, void* d_ws, size_t ws_size,
                              hipStream_t stream) {
  (void)in_sizes; (void)n_in; (void)out_size; (void)ws_size;
  const float* x     = (const float*)d_in[0];
  const float* sim   = (const float*)d_in[1];
  const float* g     = (const float*)d_in[2];
  const float* Wq    = (const float*)d_in[3];
  const float* bq    = (const float*)d_in[4];
  const float* Wk    = (const float*)d_in[5];
  const float* bk    = (const float*)d_in[6];
  const float* Wv    = (const float*)d_in[7];
  const float* bv    = (const float*)d_in[8];
  const float* Wc    = (const float*)d_in[9];
  const float* gamma = (const float*)d_in[10];
  const float* beta  = (const float*)d_in[11];
  const float* mean  = (const float*)d_in[12];
  const float* var   = (const float*)d_in[13];
  float* out = (float*)d_out;
  float* ws  = (float*)d_ws;
  float* y   = out;                    // [4][512][128][128]
  float* pcs = out + 33554432;         // [4][76][4][4]
  unsigned short* expsim  = (unsigned short*)(ws + OFF_EXPSIM);
  unsigned short* localbf = (unsigned short*)(ws + OFF_LOCALBF);
  unsigned short* Wqkt    = (unsigned short*)(ws + OFF_WQKT);
  unsigned short* vWt     = (unsigned short*)(ws + OFF_VWT);
  unsigned short* WqWkT   = (unsigned short*)(ws + OFF_WQWKT);
  unsigned short* WvWcT   = (unsigned short*)(ws + OFF_WVWCT);

  hipLaunchKernelGGL(kW_pre, dim3(65, 2), dim3(256), 0, stream,
                     Wq, Wk, Wv, Wc, bq, bk, gamma, beta, mean, var,
                     WqWkT, WvWcT, ws + OFF_WKBQ, ws + OFF_BQKADD,
                     ws + OFF_INV, ws + OFF_ADD, ws + OFF_CBB);
  hipLaunchKernelGGL(k1_stats, dim3(CMP_, 64), dim3(256), 0, stream,
                     sim, pcs, ws + OFF_CBB, expsim, ws + OFF_BK2);
  hipLaunchKernelGGL(k2_local, dim3(32, 64), dim3(256), 0, stream,
                     x, expsim, ws + OFF_WKBQ, localbf, ws + OFF_BK2);
  hipLaunchKernelGGL(k3n_wqkt, dim3(8, 64), dim3(256), 0, stream,
                     localbf, WqWkT, ws + OFF_BQKADD, Wqkt);
  hipLaunchKernelGGL(kV_vwt, dim3(8, 2), dim3(256), 0, stream,
                     WvWcT, g, bv, Wc, vWt);
  hipLaunchKernelGGL(k4_attn, dim3(16, 64), dim3(256), 0, stream,
                     x, Wqkt, ws + OFF_BK2, vWt,
                     ws + OFF_INV, ws + OFF_ADD, y);
}